// Round 9
// baseline (252.548 us; speedup 1.0000x reference)
//
#include <hip/hip_runtime.h>
#include <math.h>

#define NN 256
#define CZ 128
#define NH 4
#define CH 32
#define HC 128
#define NPIX (NN*NN)
#define L2E   1.4426950408889634f
#define SCALE2 (0.17677669529663687f * 1.4426950408889634f)   // (1/sqrt(32))*log2e

typedef __attribute__((ext_vector_type(8))) short bf16x8;   // 8 bf16 (4 VGPRs)
typedef __attribute__((ext_vector_type(4))) float fx4;      // MFMA accumulator

// --- cheap truncation split: x ~= hi + lo, total err ~2^-16 relative ---
__device__ __forceinline__ void split1(float x, short& h, short& l) {
    unsigned b  = __builtin_bit_cast(unsigned, x);
    unsigned hb = b & 0xFFFF0000u;
    float r = x - __builtin_bit_cast(float, hb);
    h = (short)(hb >> 16);
    l = (short)(__builtin_bit_cast(unsigned, r) >> 16);
}
// load 8 consecutive floats -> hi/lo bf16x8 fragments (trunc split)
__device__ __forceinline__ void load_split8(const float* p, bf16x8& h, bf16x8& l) {
    float4 x0 = *(const float4*)p;
    float4 x1 = *(const float4*)(p + 4);
    float xs[8] = {x0.x, x0.y, x0.z, x0.w, x1.x, x1.y, x1.z, x1.w};
    #pragma unroll
    for (int j = 0; j < 8; ++j) {
        short hh, ll;
        split1(xs[j], hh, ll);
        h[j] = hh; l[j] = ll;
    }
}

// ---------------------------------------------------------------------------
// Kernel 0: pack weights into MFMA B-fragment layout, bf16 hi/lo planes.
// B-frag (16x16x32): lane holds B[k][n], n=lane&15, k=quad*8+j.
// entry index: (kstep*128 + n)*4 + quad. 0=Wq 1=Wk 2=Wv 3=Wg 4=Wo.
// ---------------------------------------------------------------------------
__global__ __launch_bounds__(256) void pack_w_kernel(
    const float* __restrict__ Wq, const float* __restrict__ Wk,
    const float* __restrict__ Wv, const float* __restrict__ Wg,
    const float* __restrict__ Wo, bf16x8* __restrict__ pk)
{
    int id  = blockIdx.x * 256 + threadIdx.x;
    int mid = id >> 11;
    int e   = id & 2047;
    const float* W = (mid == 0) ? Wq : (mid == 1) ? Wk : (mid == 2) ? Wv : (mid == 3) ? Wg : Wo;
    int quad = e & 3, n = (e >> 2) & 127, ks = e >> 9;
    int k0 = ks * 32 + quad * 8;
    bf16x8 h, l;
    #pragma unroll
    for (int j = 0; j < 8; ++j) {
        float x = W[(size_t)(k0 + j) * 128 + n];
        short hh, ll;
        split1(x, hh, ll);
        h[j] = hh; l[j] = ll;
    }
    pk[(size_t)mid * 4096 + e]        = h;
    pk[(size_t)mid * 4096 + 2048 + e] = l;
}

// ---------------------------------------------------------------------------
// Kernel 1: fused LayerNorm + projections via split-bf16 MFMA.
// Outputs: bf16 hi/lo PLANES (separate short arrays, row-major):
//   q_h/q_l [i][h][j][c]   k_h/k_l [i][h][j][c]   v_h/v_l [i][h][c][j]
//   g_ws [pix][h*32+c] (fp32, sigmoid applied)
//   bias_f [h][jt][kt][lane][4] fp32 * log2e  (fragment-major, dense b128 read)
// ---------------------------------------------------------------------------
__global__ __launch_bounds__(256) void ln_proj_kernel(
    const float* __restrict__ z, const float* __restrict__ ls, const float* __restrict__ lb,
    const float* __restrict__ Wb, const bf16x8* __restrict__ pk,
    short* __restrict__ q_h, short* __restrict__ q_l,
    short* __restrict__ k_h, short* __restrict__ k_l,
    short* __restrict__ v_h, short* __restrict__ v_l,
    float* __restrict__ g_ws, float* __restrict__ bias_f)
{
    __shared__ float zsh[32][132];
    __shared__ float rsum[256], rsq[256];
    __shared__ float pmu[32], prs[32];

    const int t  = threadIdx.x;
    const int p0 = blockIdx.x * 32;
    const int i  = p0 >> 8;
    const int j0 = p0 & 255;

    const float4* z4 = (const float4*)(z + (size_t)p0 * CZ);
    #pragma unroll
    for (int r = 0; r < 4; ++r) {
        int idx4 = t + 256 * r;
        int p = idx4 >> 5, pos = idx4 & 31;
        *(float4*)&zsh[p][pos * 4] = z4[idx4];
    }
    __syncthreads();

    {
        int p = t >> 3, sg = t & 7;
        float s = 0.f, q = 0.f;
        #pragma unroll
        for (int u = 0; u < 16; ++u) { float x = zsh[p][sg * 16 + u]; s += x; q += x * x; }
        rsum[t] = s; rsq[t] = q;
    }
    __syncthreads();
    if (t < 32) {
        float s = 0.f, q = 0.f;
        #pragma unroll
        for (int g = 0; g < 8; ++g) { s += rsum[t * 8 + g]; q += rsq[t * 8 + g]; }
        float mu  = s * (1.0f / 128.0f);
        float var = q * (1.0f / 128.0f) - mu * mu;
        float a   = var + 1e-5f;
        float r   = rsqrtf(a);
        r = r * (1.5f - 0.5f * a * r * r);
        pmu[t] = mu; prs[t] = r;
    }
    __syncthreads();

    #pragma unroll
    for (int r4 = 0; r4 < 4; ++r4) {
        int idx4 = t + 256 * r4;
        int p = idx4 >> 5, pos = idx4 & 31;
        float4 v  = *(float4*)&zsh[p][pos * 4];
        float4 s4 = ((const float4*)ls)[pos];
        float4 b4 = ((const float4*)lb)[pos];
        float mu = pmu[p], rs = prs[p];
        v.x = (v.x - mu) * rs * s4.x + b4.x;
        v.y = (v.y - mu) * rs * s4.y + b4.y;
        v.z = (v.z - mu) * rs * s4.z + b4.z;
        v.w = (v.w - mu) * rs * s4.w + b4.w;
        *(float4*)&zsh[p][pos * 4] = v;
    }
    __syncthreads();

    const int wv = t >> 6, lane = t & 63;
    const int lrow = lane & 15, quad = lane >> 4;
    const bf16x8* ph = pk + (size_t)wv * 4096;
    const bf16x8* pl = ph + 2048;

    fx4 acc[2][8];
    #pragma unroll
    for (int mr = 0; mr < 2; ++mr)
        #pragma unroll
        for (int nc = 0; nc < 8; ++nc)
            acc[mr][nc] = fx4{0.f, 0.f, 0.f, 0.f};

    #pragma unroll
    for (int ks = 0; ks < 4; ++ks) {
        bf16x8 ah[2], al[2];
        #pragma unroll
        for (int mr = 0; mr < 2; ++mr)
            load_split8(&zsh[mr * 16 + lrow][ks * 32 + quad * 8], ah[mr], al[mr]);
        #pragma unroll
        for (int nc = 0; nc < 8; ++nc) {
            int bi = (ks * 128 + nc * 16 + lrow) * 4 + quad;
            bf16x8 bh = ph[bi], bl = pl[bi];
            #pragma unroll
            for (int mr = 0; mr < 2; ++mr) {
                acc[mr][nc] = __builtin_amdgcn_mfma_f32_16x16x32_bf16(ah[mr], bl, acc[mr][nc], 0, 0, 0);
                acc[mr][nc] = __builtin_amdgcn_mfma_f32_16x16x32_bf16(al[mr], bh, acc[mr][nc], 0, 0, 0);
                acc[mr][nc] = __builtin_amdgcn_mfma_f32_16x16x32_bf16(ah[mr], bh, acc[mr][nc], 0, 0, 0);
            }
        }
    }

    // epilogue: C layout col=lane&15, row=quad*4+reg
    #pragma unroll
    for (int mr = 0; mr < 2; ++mr) {
        #pragma unroll
        for (int nc = 0; nc < 8; ++nc) {
            int cg = nc * 16 + lrow;          // channel 0..127
            int h = cg >> 5, cc = cg & 31;
            int jl = mr * 16 + quad * 4;      // local pixel base (4 consecutive)
            fx4 a = acc[mr][nc];
            if (wv == 0 || wv == 1) {         // q / k : [j][c], hi+lo planes
                size_t base = ((size_t)(i * NH + h) * NN + j0 + jl) * CH + cc;
                short* dh = (wv == 0 ? q_h : k_h) + base;
                short* dl = (wv == 0 ? q_l : k_l) + base;
                #pragma unroll
                for (int r = 0; r < 4; ++r) {
                    short hs, lo; split1(a[r], hs, lo);
                    dh[r * CH] = hs; dl[r * CH] = lo;
                }
            } else if (wv == 2) {             // v transposed [c][j], hi+lo planes
                size_t base = ((size_t)(i * NH + h) * CH + cc) * NN + j0 + jl;
                short4 hv, lv;
                split1(a[0], hv.x, lv.x);
                split1(a[1], hv.y, lv.y);
                split1(a[2], hv.z, lv.z);
                split1(a[3], hv.w, lv.w);
                *(short4*)(v_h + base) = hv;
                *(short4*)(v_l + base) = lv;
            } else {                          // g (fp32)
                float* gp = g_ws + (size_t)(p0 + jl) * HC + cg;
                #pragma unroll
                for (int r = 0; r < 4; ++r) gp[r * HC] = 1.0f / (1.0f + __expf(-a[r]));
            }
        }
    }

    // bias = zn @ Wb * log2e, fragment-major: [h][jt=query>>4][kt=key>>4][lane][r]
    // this block produces bias for query=i, keys j0..j0+31
    if (t < 128) {
        int hh = t >> 5, p = t & 31;
        float b = 0.f;
        for (int d = 0; d < 128; ++d) b = fmaf(zsh[p][d], Wb[d * 4 + hh], b);
        int jt = i >> 4, lrowb = i & 15;
        int kt = (j0 + p) >> 4, quadb = (p >> 2) & 3, rr = p & 3;
        bias_f[(((size_t)(hh * 16 + jt) * 16 + kt) * 64 + quadb * 16 + lrowb) * 4 + rr] = b * L2E;
    }
}

// ---------------------------------------------------------------------------
// Kernel 2: MFMA flash attention. Block = one (i,h), 4 waves x 64 queries.
// All Q/K/V fragments load DIRECTLY as bf16 hi/lo planes (one b128 each,
// dense 1KB/instr, zero conversion VALU). Bias: one dense b128 per tile.
// S^T = K.Q^T, exp2 (no max needed: |s| < ~2), P^T hi/lo -> private LDS,
// O^T = V^T.P^T. Zero __syncthreads.
// ---------------------------------------------------------------------------
#define PSTR 40   // P row stride in ushorts
__global__ __launch_bounds__(256, 4) void attn_kernel(
    const short* __restrict__ q_h, const short* __restrict__ q_l,
    const short* __restrict__ k_h, const short* __restrict__ k_l,
    const short* __restrict__ v_h, const short* __restrict__ v_l,
    const float* __restrict__ g_ws, const float* __restrict__ bias_f,
    float* __restrict__ go_ws)
{
    __shared__ unsigned short Psh[4][2][64 * PSTR];   // 40 KB

    const int t = threadIdx.x;
    const int wv = t >> 6, lane = t & 63;
    const int lrow = lane & 15, quad = lane >> 4;
    const int h = blockIdx.x & 3, i = blockIdx.x >> 2;
    const int qb = wv * 64;

    const size_t slab  = (size_t)(i * NH + h) * NN * CH;
    const short* qsh = q_h + slab;  const short* qsl = q_l + slab;
    const short* ksh = k_h + slab;  const short* ksl = k_l + slab;
    const short* vsh = v_h + slab;  const short* vsl = v_l + slab;
    // bias base for this (h, wv): index = (h*16 + jt)*4096 + kt*256 + lane*4, jt = wv*4+nt
    const float* bbase = bias_f + (size_t)(h * 16 + wv * 4) * 4096 + lane * 4;

    // Q B-frags: lane holds Q^T[k=c=quad*8+j][n=query=lrow]
    bf16x8 qh[4], ql[4];
    #pragma unroll
    for (int nt = 0; nt < 4; ++nt) {
        size_t o = (size_t)(qb + nt * 16 + lrow) * CH + quad * 8;
        qh[nt] = *(const bf16x8*)(qsh + o);
        ql[nt] = *(const bf16x8*)(qsl + o);
    }

    fx4 oacc[2][4];   // [c-tile][q-tile], O^T C-layout
    #pragma unroll
    for (int ct = 0; ct < 2; ++ct)
        #pragma unroll
        for (int nt = 0; nt < 4; ++nt)
            oacc[ct][nt] = fx4{0.f, 0.f, 0.f, 0.f};
    float lsum[4] = {0.f, 0.f, 0.f, 0.f};

    for (int kb = 0; kb < NN; kb += 32) {
        const int kt0 = kb >> 4;
        // K A-frags: lane holds K[m=key=lrow][k=c=quad*8+j]
        bf16x8 kh[2], kl_[2];
        #pragma unroll
        for (int mt = 0; mt < 2; ++mt) {
            size_t o = (size_t)(kb + mt * 16 + lrow) * CH + quad * 8;
            kh[mt]  = *(const bf16x8*)(ksh + o);
            kl_[mt] = *(const bf16x8*)(ksl + o);
        }
        // V A-frags: lane holds V^T[m=c=lrow][k=key=quad*8+j]
        bf16x8 vh[2], vl[2];
        #pragma unroll
        for (int ct = 0; ct < 2; ++ct) {
            size_t o = (size_t)(ct * 16 + lrow) * NN + kb + quad * 8;
            vh[ct] = *(const bf16x8*)(vsh + o);
            vl[ct] = *(const bf16x8*)(vsl + o);
        }

        // scores S^T tiles: rows=keys, cols=queries
        #pragma unroll
        for (int nt = 0; nt < 4; ++nt) {
            #pragma unroll
            for (int mt = 0; mt < 2; ++mt) {
                float4 bv = *(const float4*)(bbase + (size_t)(nt * 16 + kt0 + mt) * 256);

                fx4 sv = fx4{0.f, 0.f, 0.f, 0.f};
                sv = __builtin_amdgcn_mfma_f32_16x16x32_bf16(kh[mt], ql[nt], sv, 0, 0, 0);
                sv = __builtin_amdgcn_mfma_f32_16x16x32_bf16(kl_[mt], qh[nt], sv, 0, 0, 0);
                sv = __builtin_amdgcn_mfma_f32_16x16x32_bf16(kh[mt], qh[nt], sv, 0, 0, 0);

                float e0 = exp2f(fmaf(sv[0], SCALE2, bv.x));
                float e1 = exp2f(fmaf(sv[1], SCALE2, bv.y));
                float e2 = exp2f(fmaf(sv[2], SCALE2, bv.z));
                float e3 = exp2f(fmaf(sv[3], SCALE2, bv.w));
                lsum[nt] += (e0 + e1) + (e2 + e3);

                unsigned b0 = __builtin_bit_cast(unsigned, e0);
                unsigned b1 = __builtin_bit_cast(unsigned, e1);
                unsigned b2 = __builtin_bit_cast(unsigned, e2);
                unsigned b3 = __builtin_bit_cast(unsigned, e3);
                // hi pack: bytes [b0.2,b0.3,b1.2,b1.3] via v_perm
                unsigned h01 = __builtin_amdgcn_perm(b1, b0, 0x07060302u);
                unsigned h23 = __builtin_amdgcn_perm(b3, b2, 0x07060302u);
                float r0 = e0 - __builtin_bit_cast(float, b0 & 0xFFFF0000u);
                float r1 = e1 - __builtin_bit_cast(float, b1 & 0xFFFF0000u);
                float r2 = e2 - __builtin_bit_cast(float, b2 & 0xFFFF0000u);
                float r3 = e3 - __builtin_bit_cast(float, b3 & 0xFFFF0000u);
                unsigned l01 = __builtin_amdgcn_perm(__builtin_bit_cast(unsigned, r1),
                                                     __builtin_bit_cast(unsigned, r0), 0x07060302u);
                unsigned l23 = __builtin_amdgcn_perm(__builtin_bit_cast(unsigned, r3),
                                                     __builtin_bit_cast(unsigned, r2), 0x07060302u);

                int wo = (nt * 16 + lrow) * PSTR + mt * 16 + quad * 4;
                *(uint2*)&Psh[wv][0][wo] = make_uint2(h01, h23);
                *(uint2*)&Psh[wv][1][wo] = make_uint2(l01, l23);
            }
        }

        // PV: P^T B-frags from LDS (same-wave; compiler inserts lgkmcnt waits)
        #pragma unroll
        for (int nt = 0; nt < 4; ++nt) {
            bf16x8 pbh = *(const bf16x8*)&Psh[wv][0][(nt * 16 + lrow) * PSTR + quad * 8];
            bf16x8 pbl = *(const bf16x8*)&Psh[wv][1][(nt * 16 + lrow) * PSTR + quad * 8];
            #pragma unroll
            for (int ct = 0; ct < 2; ++ct) {
                oacc[ct][nt] = __builtin_amdgcn_mfma_f32_16x16x32_bf16(vh[ct], pbl, oacc[ct][nt], 0, 0, 0);
                oacc[ct][nt] = __builtin_amdgcn_mfma_f32_16x16x32_bf16(vl[ct], pbh, oacc[ct][nt], 0, 0, 0);
                oacc[ct][nt] = __builtin_amdgcn_mfma_f32_16x16x32_bf16(vh[ct], pbh, oacc[ct][nt], 0, 0, 0);
            }
        }
    }

    // epilogue: reduce l over quads, gate, store. O^T: col=query=lrow, row=c=quad*4+r
    #pragma unroll
    for (int nt = 0; nt < 4; ++nt) {
        float s = lsum[nt];
        s += __shfl_xor(s, 16, 64);
        s += __shfl_xor(s, 32, 64);
        float inv = 1.0f / s;
        size_t pix = (size_t)i * NN + qb + nt * 16 + lrow;
        #pragma unroll
        for (int ct = 0; ct < 2; ++ct) {
            const float* gp = g_ws + pix * HC + h * CH + ct * 16 + quad * 4;
            float4 g4 = *(const float4*)gp;
            fx4 o = oacc[ct][nt];
            float4 r;
            r.x = g4.x * o[0] * inv;
            r.y = g4.y * o[1] * inv;
            r.z = g4.z * o[2] * inv;
            r.w = g4.w * o[3] * inv;
            *(float4*)(go_ws + pix * HC + h * CH + ct * 16 + quad * 4) = r;
        }
    }
}

// ---------------------------------------------------------------------------
// Kernel 3: out = go @ Wo via split-bf16 MFMA.
// ---------------------------------------------------------------------------
__global__ __launch_bounds__(256) void outproj_kernel(
    const float* __restrict__ go_ws, const bf16x8* __restrict__ pk, float* __restrict__ out)
{
    __shared__ float gsh[64][132];
    const int t  = threadIdx.x;
    const int p0 = blockIdx.x * 64;

    const float4* g4 = (const float4*)(go_ws + (size_t)p0 * HC);
    #pragma unroll
    for (int r = 0; r < 8; ++r) {
        int idx4 = t + 256 * r;
        int p = idx4 >> 5, pos = idx4 & 31;
        *(float4*)&gsh[p][pos * 4] = g4[idx4];
    }
    __syncthreads();

    const int wv = t >> 6, lane = t & 63;
    const int lrow = lane & 15, quad = lane >> 4;
    const bf16x8* ph = pk + (size_t)4 * 4096;   // Wo
    const bf16x8* pl = ph + 2048;

    fx4 acc[8];
    #pragma unroll
    for (int nc = 0; nc < 8; ++nc) acc[nc] = fx4{0.f, 0.f, 0.f, 0.f};

    #pragma unroll
    for (int ks = 0; ks < 4; ++ks) {
        bf16x8 ah, al;
        load_split8(&gsh[wv * 16 + lrow][ks * 32 + quad * 8], ah, al);
        #pragma unroll
        for (int nc = 0; nc < 8; ++nc) {
            int bi = (ks * 128 + nc * 16 + lrow) * 4 + quad;
            bf16x8 bh = ph[bi], bl = pl[bi];
            acc[nc] = __builtin_amdgcn_mfma_f32_16x16x32_bf16(ah, bl, acc[nc], 0, 0, 0);
            acc[nc] = __builtin_amdgcn_mfma_f32_16x16x32_bf16(al, bh, acc[nc], 0, 0, 0);
            acc[nc] = __builtin_amdgcn_mfma_f32_16x16x32_bf16(ah, bh, acc[nc], 0, 0, 0);
        }
    }

    #pragma unroll
    for (int nc = 0; nc < 8; ++nc) {
        #pragma unroll
        for (int r = 0; r < 4; ++r)
            out[(size_t)(p0 + wv * 16 + quad * 4 + r) * HC + nc * 16 + lrow] = acc[nc][r];
    }
}

// ---------------------------------------------------------------------------
extern "C" void kernel_launch(void* const* d_in, const int* in_sizes, int n_in,
                              void* d_out, int out_size, void* d_ws, size_t ws_size,
                              hipStream_t stream)
{
    const float* z  = (const float*)d_in[0];
    const float* ls = (const float*)d_in[1];
    const float* lb = (const float*)d_in[2];
    const float* Wq = (const float*)d_in[3];
    const float* Wk = (const float*)d_in[4];
    const float* Wv = (const float*)d_in[5];
    const float* Wb = (const float*)d_in[6];
    const float* Wg = (const float*)d_in[7];
    const float* Wo = (const float*)d_in[8];

    float* ws = (float*)d_ws;
    const size_t BIG = (size_t)NPIX * HC;   // 8.4M elements
    short* q_h = (short*)ws;                // 6 short planes = 3 BIG floats
    short* q_l = q_h + BIG;
    short* k_h = q_l + BIG;
    short* k_l = k_h + BIG;
    short* v_h = k_l + BIG;
    short* v_l = v_h + BIG;
    float* g_ws   = ws + 3 * BIG;
    float* go_ws  = ws + 4 * BIG;
    float* bias_f = ws + 5 * BIG;                              // NH*NPIX floats
    bf16x8* pk    = (bf16x8*)(bias_f + (size_t)NH * NPIX);     // 5 x 64 KB packs

    pack_w_kernel<<<40, 256, 0, stream>>>(Wq, Wk, Wv, Wg, Wo, pk);
    ln_proj_kernel<<<NPIX / 32, 256, 0, stream>>>(z, ls, lb, Wb, pk,
                                                  q_h, q_l, k_h, k_l, v_h, v_l,
                                                  g_ws, bias_f);
    attn_kernel<<<NN * NH, 256, 0, stream>>>(q_h, q_l, k_h, k_l, v_h, v_l,
                                             g_ws, bias_f, go_ws);
    outproj_kernel<<<NPIX / 64, 256, 0, stream>>>(go_ws, pk, (float*)d_out);
}